// Round 1
// 213.601 us; speedup vs baseline: 1.0066x; 1.0066x over previous
//
#include <hip/hip_runtime.h>
#include <stdint.h>

#define T_SEQ 2048
#define D_MODEL 1024
#define NH 16
#define DH 64
#define NROWS 4096  // B*T

typedef __bf16 bf16x8 __attribute__((ext_vector_type(8)));
typedef float floatx4 __attribute__((ext_vector_type(4)));
typedef short short4v __attribute__((ext_vector_type(4)));
typedef short short8v __attribute__((ext_vector_type(8)));

#define AS1 __attribute__((address_space(1)))
#define AS3 __attribute__((address_space(3)))

static __device__ __forceinline__ void gl2lds16(const unsigned short* g, unsigned short* s) {
    __builtin_amdgcn_global_load_lds((const AS1 unsigned int*)g, (AS3 unsigned int*)s, 16, 0, 0);
}

static __device__ __forceinline__ unsigned short f32_bf16(float f) {
    union { float f; unsigned int u; } c; c.f = f;
    unsigned int u = c.u;
    u = u + 0x7FFFu + ((u >> 16) & 1u);   // RNE
    return (unsigned short)(u >> 16);
}

static __device__ __forceinline__ unsigned int pack2_bf16(float a, float b) {
    return (unsigned int)f32_bf16(a) | ((unsigned int)f32_bf16(b) << 16);
}

static __device__ __forceinline__ floatx4 mfma16(bf16x8 a, bf16x8 b, floatx4 c) {
    return __builtin_amdgcn_mfma_f32_16x16x32_bf16(a, b, c, 0, 0, 0);
}

static __device__ __forceinline__ floatx4 mfma16k16(short4v a, short4v b, floatx4 c) {
#if defined(__HIP_DEVICE_COMPILE__)
    return __builtin_amdgcn_mfma_f32_16x16x16bf16_1k(a, b, c, 0, 0, 0);
#else
    (void)a; (void)b;
    return c;  // host stub — never executed
#endif
}

#define QSCALE 0.1803368801111204f   // (1/8) * log2(e); softmax in exp2 domain
#define EXP2_SHIFT 10.0f
// s_waitcnt imm: vmcnt[3:0], expcnt[6:4]=7 (nowait), lgkmcnt[11:8]=0xF (nowait)
#define WAITCNT_VM(n) (0x0F70 | (n))

// ---------------- fused conversion kernel ----------------
__global__ __launch_bounds__(256) void k_conv_all(const float* __restrict__ x,
                                                  const float* __restrict__ Wq,
                                                  const float* __restrict__ Wk,
                                                  const float* __restrict__ Wv,
                                                  const float* __restrict__ Wo,
                                                  unsigned short* __restrict__ x_bf,
                                                  unsigned short* __restrict__ wqkv_bf,
                                                  unsigned short* __restrict__ wo_bf) {
    int b = blockIdx.x, t = threadIdx.x;
    if (b < 4096) {
        int i = b * 1024 + t * 4;
        float4 v = *(const float4*)(x + i);
        uint2 o;
        o.x = pack2_bf16(v.x, v.y);
        o.y = pack2_bf16(v.z, v.w);
        *(uint2*)(x_bf + i) = o;
    } else if (b < 7168) {
        int idx = b - 4096;
        int tensor = idx >> 10, np = idx & 1023;
        const float* src = tensor == 0 ? Wq : tensor == 1 ? Wk : Wv;
        int f = (np & 63) * 16 + (np >> 6);
        int c = t * 4;
        float4 v = *(const float4*)(src + (long)f * D_MODEL + c);
        uint2 o;
        o.x = pack2_bf16(v.x, v.y);
        o.y = pack2_bf16(v.z, v.w);
        *(uint2*)(wqkv_bf + ((long)tensor * D_MODEL + np) * D_MODEL + c) = o;
    } else {
        int n = b - 7168;
        int fp = t * 4;
        const float* row = Wo + (long)n * D_MODEL;
        unsigned short o[4];
        #pragma unroll
        for (int k = 0; k < 4; k++) {
            int f = fp + k;
            o[k] = f32_bf16(row[(f & 63) * 16 + (f >> 6)]);
        }
        *(uint2*)(wo_bf + (long)n * D_MODEL + fp) = *(const uint2*)o;
    }
}

// ---------------- GEMM: C = A(bf16) @ W(bf16)^T, K = 1024 ----------------
// Double-buffered LDS K-loop; raw s_barrier + manual partial vmcnt — no compiler
// vmcnt(0) drains anywhere in the loop. XOR-swizzled LDS, XCD-aware block swizzle.
// MODE 0: fused QKV (W stacked 3072x1024); grid 768. MODE 1: O-proj; grid 512.
template <int BN, int MODE>
__global__ __launch_bounds__(256) void k_gemm(const unsigned short* __restrict__ A,
                                              const unsigned short* __restrict__ W,
                                              const float* __restrict__ b0,
                                              const float* __restrict__ b1,
                                              const float* __restrict__ b2,
                                              const float* __restrict__ resid,
                                              unsigned short* __restrict__ out_bf,
                                              unsigned short* __restrict__ vtg,
                                              float* __restrict__ out_f32) {
    constexpr int NT = BN / 32;
    constexpr int NCB = BN / 32;
    constexpr int NDMA = 4 + NCB;            // DMA instrs per thread per stage
    __shared__ unsigned short lds_a[2 * 128 * 64];
    __shared__ unsigned short lds_b[2 * BN * 64];
    const int tid = threadIdx.x;
    const int w = tid >> 6, l = tid & 63;
    const int lrow = l & 15, lq = l >> 4;
    const int wm = (w >> 1) * 64, wn = (w & 1) * (BN / 2);
    const int L = blockIdx.x;
    const int bx = (L & 7) * 4 + ((L >> 3) & 3);
    const int by = L >> 5;
    const long am0 = (long)bx * 128;
    const long wn0 = (long)by * BN;

    floatx4 acc[4][NT] = {};
    const int grow = l >> 3;
    const int gcol = ((l & 7) ^ grow) * 8;   // column-group XOR swizzle (global side)
    const int sw8 = (lrow & 7);

    auto stage = [&](int ki, int sel) {
        unsigned short* la = lds_a + sel * 8192;
        unsigned short* lb = lds_b + sel * (BN * 64);
        int k0 = ki * 64;
        #pragma unroll
        for (int c = 0; c < 4; c++) {
            int chunk = w * 4 + c;
            gl2lds16(A + (am0 + chunk * 8 + grow) * D_MODEL + k0 + gcol, la + chunk * 512);
        }
        #pragma unroll
        for (int c = 0; c < NCB; c++) {
            int chunk = w * NCB + c;
            gl2lds16(W + (wn0 + chunk * 8 + grow) * D_MODEL + k0 + gcol, lb + chunk * 512);
        }
    };

    stage(0, 0);

    for (int i = 0; i < 16; i++) {
        const int cur = i & 1;
        if (i < 15) {
            stage(i + 1, 1 - cur);
            __builtin_amdgcn_s_waitcnt(WAITCNT_VM(NDMA));  // drain stage(i), keep stage(i+1)
        } else {
            __builtin_amdgcn_s_waitcnt(WAITCNT_VM(0));
        }
        __builtin_amdgcn_s_barrier();

        const unsigned short* la = lds_a + cur * 8192;
        const unsigned short* lb = lds_b + cur * (BN * 64);
        bf16x8 af[4][2], bf[NT][2];
        #pragma unroll
        for (int mt = 0; mt < 4; mt++)
            #pragma unroll
            for (int ks = 0; ks < 2; ks++)
                af[mt][ks] = *(const bf16x8*)(la + (wm + mt * 16 + lrow) * 64 +
                                              (((ks * 4 + lq) ^ sw8) * 8));
        #pragma unroll
        for (int nt = 0; nt < NT; nt++)
            #pragma unroll
            for (int ks = 0; ks < 2; ks++)
                bf[nt][ks] = *(const bf16x8*)(lb + (wn + nt * 16 + lrow) * 64 +
                                              (((ks * 4 + lq) ^ sw8) * 8));
        #pragma unroll
        for (int mt = 0; mt < 4; mt++)
            #pragma unroll
            for (int nt = 0; nt < NT; nt++)
                #pragma unroll
                for (int ks = 0; ks < 2; ks++)
                    acc[mt][nt] = mfma16(af[mt][ks], bf[nt][ks], acc[mt][nt]);
        __builtin_amdgcn_s_barrier();   // raw: reads of buf[cur] done before restage (i+2)
    }

    if (MODE == 0) {
        int tensor = by >> 3;                    // 0=Q 1=K 2=V
        int nbase = (by & 7) * 128;
        const float* bias = tensor == 0 ? b0 : tensor == 1 ? b1 : b2;
        float scale = tensor == 0 ? QSCALE : 1.0f;
        if (tensor < 2) {
            unsigned short* outt = out_bf + (size_t)tensor * (32u * T_SEQ * DH);
            #pragma unroll
            for (int mt = 0; mt < 4; mt++) {
                #pragma unroll
                for (int nt = 0; nt < NT; nt++) {
                    int n = nbase + wn + nt * 16 + lrow;     // n' = h*64+d
                    int h = n >> 6, d = n & 63;
                    float bb = bias[d * 16 + h];
                    #pragma unroll
                    for (int r = 0; r < 4; r++) {
                        int row = (int)am0 + wm + mt * 16 + lq * 4 + r;
                        float v = (acc[mt][nt][r] + bb) * scale;
                        int b = row >> 11, i = row & 2047;
                        long idx = ((long)(b * 16 + h) * T_SEQ + i) * DH + d;
                        outt[idx] = f32_bf16(v);
                    }
                }
            }
        } else {
            int row0 = (int)am0 + wm;                    // multiple of 64
            int b = row0 >> 11;
            int blk = (row0 & 2047) >> 6;
            #pragma unroll
            for (int nt = 0; nt < NT; nt++) {
                int n = nbase + wn + nt * 16 + lrow;
                int h = n >> 6, d = n & 63;
                float bb = bias[d * 16 + h];
                long base = (((long)(b * 16 + h) * 64 + d) * 32 + blk) * 64;
                #pragma unroll
                for (int mt = 0; mt < 4; mt++) {
                    uint2 o;
                    o.x = pack2_bf16(acc[mt][nt][0] + bb, acc[mt][nt][1] + bb);
                    o.y = pack2_bf16(acc[mt][nt][2] + bb, acc[mt][nt][3] + bb);
                    *(uint2*)(vtg + base + lq * 16 + mt * 4) = o;
                }
            }
        }
    } else {
        #pragma unroll
        for (int mt = 0; mt < 4; mt++) {
            #pragma unroll
            for (int nt = 0; nt < NT; nt++) {
                int n = (int)wn0 + wn + nt * 16 + lrow;
                float bb = b0[n];
                #pragma unroll
                for (int r = 0; r < 4; r++) {
                    int row = (int)am0 + wm + mt * 16 + lq * 4 + r;
                    long idx = (long)row * D_MODEL + n;
                    out_f32[idx] = acc[mt][nt][r] + bb + resid[idx];
                }
            }
        }
    }
}

// ---------------- attention: S^T trick + cross-tile software pipeline --------
// r7 structure: per iteration, QK^T(t) MFMAs are followed by an interleaved
// region { PV(t-1) k16-MFMAs ∥ exp2/pack(t) TRANS/VALU } — the two are
// independent, so the scheduler can keep the MFMA and VALU pipes busy
// simultaneously (they were serialized before: MfmaUtil 40 + VALUBusy 46).
// V staging is shifted one tile later than K (stage pair = K(t+1), V(t));
// double P-state (pA/pB) rotated by an explicitly paired loop (no reg copies).
// Accumulation order is bitwise identical to the previous version.
__global__ __launch_bounds__(256) void k_attn(const unsigned short* __restrict__ q_ws,
                                              const unsigned short* __restrict__ k_ws,
                                              const unsigned short* __restrict__ vtg,
                                              unsigned short* __restrict__ att) {
    __shared__ unsigned short kbuf[2 * 64 * 64];
    __shared__ unsigned short vbuf[2 * 64 * 64];
    const int tid = threadIdx.x;
    const int w = tid >> 6, l = tid & 63;
    const int lrow = l & 15, lq = l >> 4;
    const int sw = lrow & 7;
    const int L = blockIdx.x;
    const int bh = (L & 7) * 4 + ((L >> 3) & 3);   // 4 bh per XCD -> K/V L2-resident
    const int i0 = (L >> 5) * 128;
    const unsigned short* kh = k_ws + (long)bh * T_SEQ * DH;
    const unsigned short* vh = vtg + (long)bh * 64 * T_SEQ;  // [d][blk][j']

    const int rl = l >> 3;                     // staging: row within 8-row chunk
    const int gl = ((l & 7) ^ rl) * 8;         // staging: swizzled granule (shorts)

    bf16x8 qf[2][2];
    #pragma unroll
    for (int qt = 0; qt < 2; qt++) {
        const unsigned short* qp =
            q_ws + ((long)bh * T_SEQ + i0 + w * 32 + qt * 16 + lrow) * DH + lq * 8;
        qf[qt][0] = *(const bf16x8*)qp;
        qf[qt][1] = *(const bf16x8*)(qp + 32);
    }
    floatx4 o_acc[2][4] = {};
    floatx4 l_acc[2] = {};
    const short4v ones = {0x3F80, 0x3F80, 0x3F80, 0x3F80};

    auto stage_k = [&](int jt, int sel) {
        unsigned short* kd = kbuf + sel * 4096 + (w * 2) * 512;
        #pragma unroll
        for (int c = 0; c < 2; c++) {
            int row = w * 16 + c * 8 + rl;     // 0..63
            gl2lds16(kh + ((long)(jt * 64 + row)) * 64 + gl, kd + c * 512);
        }
    };
    auto stage_v = [&](int jt, int sel) {
        unsigned short* vd = vbuf + sel * 4096 + (w * 2) * 512;
        #pragma unroll
        for (int c = 0; c < 2; c++) {
            int row = w * 16 + c * 8 + rl;
            gl2lds16(vh + ((long)row * 32 + jt) * 64 + gl, vd + c * 512);
        }
    };

    // S^T - 10 for both q-tiles; K-frags read once (single-granule b128s)
    auto qk = [&](const unsigned short* kb_, floatx4 (&s0)[4], floatx4 (&s1)[4]) {
        #pragma unroll
        for (int nt = 0; nt < 4; nt++) {
            const unsigned short* kp = kb_ + (nt * 16 + lrow) * 64;
            bf16x8 ka = *(const bf16x8*)(kp + ((lq ^ sw) * 8));
            bf16x8 kb = *(const bf16x8*)(kp + (((lq + 4) ^ sw) * 8));
            floatx4 c0 = {-EXP2_SHIFT, -EXP2_SHIFT, -EXP2_SHIFT, -EXP2_SHIFT};
            floatx4 c1 = c0;
            c0 = mfma16(ka, qf[0][0], c0);
            c0 = mfma16(kb, qf[0][1], c0);
            c1 = mfma16(ka, qf[1][0], c1);
            c1 = mfma16(kb, qf[1][1], c1);
            s0[nt] = c0;
            s1[nt] = c1;
        }
    };

    // p = exp2(s); pack bf16 B-frag (truncation via perm); denominator ones-MFMA
    auto softpack = [&](floatx4 s, short4v& pf, int qt) {
        float p0 = __builtin_amdgcn_exp2f(s[0]);
        float p1 = __builtin_amdgcn_exp2f(s[1]);
        float p2 = __builtin_amdgcn_exp2f(s[2]);
        float p3 = __builtin_amdgcn_exp2f(s[3]);
        uint2 pk;
        pk.x = __builtin_amdgcn_perm(__float_as_uint(p1), __float_as_uint(p0), 0x07060302);
        pk.y = __builtin_amdgcn_perm(__float_as_uint(p3), __float_as_uint(p2), 0x07060302);
        union { uint2 u; short4v s4; } cv; cv.u = pk;
        pf = cv.s4;
        l_acc[qt] = mfma16k16(ones, pf, l_acc[qt]);
    };

    // O^T += V^T * P for one dt, both q-tiles (V-frags single-granule reads)
    auto pv_dt = [&](const unsigned short* vb_, int dt,
                     short4v (&p0)[4], short4v (&p1)[4]) {
        const unsigned short* vp = vb_ + (dt * 16 + lrow) * 64;
        short8v v01 = *(const short8v*)(vp + (((2 * lq) ^ sw) * 8));
        short8v v23 = *(const short8v*)(vp + (((2 * lq + 1) ^ sw) * 8));
        short4v va = __builtin_shufflevector(v01, v01, 0, 1, 2, 3);
        short4v vb = __builtin_shufflevector(v01, v01, 4, 5, 6, 7);
        short4v vc = __builtin_shufflevector(v23, v23, 0, 1, 2, 3);
        short4v vd = __builtin_shufflevector(v23, v23, 4, 5, 6, 7);
        o_acc[0][dt] = mfma16k16(va, p0[0], o_acc[0][dt]);
        o_acc[0][dt] = mfma16k16(vb, p0[1], o_acc[0][dt]);
        o_acc[0][dt] = mfma16k16(vc, p0[2], o_acc[0][dt]);
        o_acc[0][dt] = mfma16k16(vd, p0[3], o_acc[0][dt]);
        o_acc[1][dt] = mfma16k16(va, p1[0], o_acc[1][dt]);
        o_acc[1][dt] = mfma16k16(vb, p1[1], o_acc[1][dt]);
        o_acc[1][dt] = mfma16k16(vc, p1[2], o_acc[1][dt]);
        o_acc[1][dt] = mfma16k16(vd, p1[3], o_acc[1][dt]);
    };

    // one pipelined tile: QK(t) then { PV(t-1) ∥ exp2/pack(t) } interleaved
    auto tile_body = [&](const unsigned short* kb_, const unsigned short* vb_,
                         short4v (&pp0)[4], short4v (&pp1)[4],
                         short4v (&pc0)[4], short4v (&pc1)[4]) {
        floatx4 s0[4], s1[4];
        qk(kb_, s0, s1);
        #pragma unroll
        for (int dt = 0; dt < 4; dt++) {
            pv_dt(vb_, dt, pp0, pp1);         // MFMA pipe (prev tile's P)
            softpack(s0[dt], pc0[dt], 0);     // TRANS/VALU (this tile's P)
            softpack(s1[dt], pc1[dt], 1);
        }
    };

    short4v pA0[4], pA1[4], pB0[4], pB1[4];

    // ---- prologue: tile 0 (no PV yet). Stage K(0); then K(1)+V(0) in flight.
    stage_k(0, 0);
    stage_k(1, 1);
    stage_v(0, 0);
    __builtin_amdgcn_s_waitcnt(WAITCNT_VM(4));   // drain qf + K(0), keep K(1)+V(0)
    __builtin_amdgcn_s_barrier();
    {
        floatx4 s0[4], s1[4];
        qk(kbuf, s0, s1);
        #pragma unroll
        for (int dt = 0; dt < 4; dt++) {
            softpack(s0[dt], pA0[dt], 0);
            softpack(s1[dt], pA1[dt], 1);
        }
    }
    __builtin_amdgcn_s_barrier();   // all waves done reading kbuf[0] before restage

    // ---- main loop: tiles 1..30, explicitly paired so P-state rotates in regs
    for (int t = 1; t < 31; t += 2) {
        // tile t (odd): consume pA -> produce pB
        stage_k(t + 1, (t + 1) & 1);
        stage_v(t, t & 1);
        __builtin_amdgcn_s_waitcnt(WAITCNT_VM(4));   // drain K(t)+V(t-1)
        __builtin_amdgcn_s_barrier();
        tile_body(kbuf + (t & 1) * 4096, vbuf + ((t - 1) & 1) * 4096,
                  pA0, pA1, pB0, pB1);
        __builtin_amdgcn_s_barrier();
        // tile t+1 (even): consume pB -> produce pA
        stage_k(t + 2, t & 1);
        stage_v(t + 1, (t + 1) & 1);
        __builtin_amdgcn_s_waitcnt(WAITCNT_VM(4));   // drain K(t+1)+V(t)
        __builtin_amdgcn_s_barrier();
        tile_body(kbuf + ((t + 1) & 1) * 4096, vbuf + (t & 1) * 4096,
                  pB0, pB1, pA0, pA1);
        __builtin_amdgcn_s_barrier();
    }

    // ---- tile 31 (last): stage V(31) only; consume pA -> produce pB
    stage_v(31, 1);
    __builtin_amdgcn_s_waitcnt(WAITCNT_VM(2));       // drain K(31)+V(30), keep V(31)
    __builtin_amdgcn_s_barrier();
    tile_body(kbuf + 4096, vbuf + 0, pA0, pA1, pB0, pB1);
    __builtin_amdgcn_s_barrier();

    // ---- epilogue: PV(31)
    __builtin_amdgcn_s_waitcnt(WAITCNT_VM(0));       // own V(31) DMA done
    __builtin_amdgcn_s_barrier();                    // everyone's V(31) DMA done
    #pragma unroll
    for (int dt = 0; dt < 4; dt++) pv_dt(vbuf + 4096, dt, pB0, pB1);

    int h = bh & 15, b = bh >> 4;
    #pragma unroll
    for (int qt = 0; qt < 2; qt++) {
        float rl2 = 1.0f / l_acc[qt][0];
        int i = i0 + w * 32 + qt * 16 + lrow;
        unsigned short* orow = att + ((long)(b * T_SEQ + i)) * D_MODEL + h * 64;
        #pragma unroll
        for (int dt = 0; dt < 4; dt++) {
            uint2 o;
            o.x = pack2_bf16(o_acc[qt][dt][0] * rl2, o_acc[qt][dt][1] * rl2);
            o.y = pack2_bf16(o_acc[qt][dt][2] * rl2, o_acc[qt][dt][3] * rl2);
            *(uint2*)(orow + dt * 16 + lq * 4) = o;
        }
    }
}

// ---------------- LayerNorm in-place on d_out ----------------
__global__ __launch_bounds__(256) void k_ln(float* __restrict__ io,
                                            const float* __restrict__ gamma,
                                            const float* __restrict__ beta) {
    int row = blockIdx.x, t = threadIdx.x;
    float* p = io + (long)row * D_MODEL + t * 4;
    float4 v = *(float4*)p;
    float s = v.x + v.y + v.z + v.w;
    float ss = v.x * v.x + v.y * v.y + v.z * v.z + v.w * v.w;
    #pragma unroll
    for (int m = 1; m < 64; m <<= 1) {
        s += __shfl_xor(s, m);
        ss += __shfl_xor(ss, m);
    }
    __shared__ float red[8];
    if ((t & 63) == 0) { red[t >> 6] = s; red[4 + (t >> 6)] = ss; }
    __syncthreads();
    s = red[0] + red[1] + red[2] + red[3];
    ss = red[4] + red[5] + red[6] + red[7];
    float mu = s * (1.0f / 1024.0f);
    float var = ss * (1.0f / 1024.0f) - mu * mu;
    float rstd = rsqrtf(var + 1e-5f);
    float4 g = *(const float4*)(gamma + t * 4);
    float4 be = *(const float4*)(beta + t * 4);
    float4 o;
    o.x = (v.x - mu) * rstd * g.x + be.x;
    o.y = (v.y - mu) * rstd * g.y + be.y;
    o.z = (v.z - mu) * rstd * g.z + be.z;
    o.w = (v.w - mu) * rstd * g.w + be.w;
    *(float4*)p = o;
}

extern "C" void kernel_launch(void* const* d_in, const int* in_sizes, int n_in,
                              void* d_out, int out_size, void* d_ws, size_t ws_size,
                              hipStream_t stream) {
    const float* x = (const float*)d_in[0];
    const float* Wq = (const float*)d_in[1];
    const float* bq = (const float*)d_in[2];
    const float* Wk = (const float*)d_in[3];
    const float* bk = (const float*)d_in[4];
    const float* Wv = (const float*)d_in[5];
    const float* bv = (const float*)d_in[6];
    const float* Wo = (const float*)d_in[7];
    const float* bo = (const float*)d_in[8];
    const float* gamma = (const float*)d_in[9];
    const float* beta = (const float*)d_in[10];
    float* out = (float*)d_out;

    char* ws = (char*)d_ws;
    unsigned short* x_bf = (unsigned short*)(ws);                       // 0-8 MB (reused as att)
    unsigned short* wqkv_bf = (unsigned short*)(ws + ((size_t)8 << 20));// 8-14 MB
    unsigned short* wo_bf = (unsigned short*)(ws + ((size_t)14 << 20)); // 14-16 MB
    unsigned short* qkv_ws = (unsigned short*)(ws + ((size_t)16 << 20));// 16-40 MB (q|k|vt)
    unsigned short* att = x_bf;  // alias: x_bf dead after QKV GEMM

    unsigned short* q_ws = qkv_ws;
    unsigned short* k_ws = qkv_ws + (size_t)32 * T_SEQ * DH;
    unsigned short* vtg = qkv_ws + (size_t)64 * T_SEQ * DH;

    k_conv_all<<<8192, 256, 0, stream>>>(x, Wq, Wk, Wv, Wo, x_bf, wqkv_bf, wo_bf);

    // fused QKV GEMM: N = 3072, 1D grid with XCD swizzle
    k_gemm<128, 0><<<768, 256, 0, stream>>>(
        x_bf, wqkv_bf, bq, bk, bv, nullptr, qkv_ws, vtg, nullptr);

    k_attn<<<512, 256, 0, stream>>>(q_ws, k_ws, vtg, att);

    // O-projection + bias + residual: N = 1024, 1D grid with XCD swizzle
    k_gemm<64, 1><<<512, 256, 0, stream>>>(
        att, wo_bf, bo, nullptr, nullptr, x, nullptr, nullptr, out);

    k_ln<<<NROWS, 256, 0, stream>>>(out, gamma, beta);
}

// Round 2
// 202.720 us; speedup vs baseline: 1.0606x; 1.0537x over previous
//
#include <hip/hip_runtime.h>
#include <stdint.h>

#define T_SEQ 2048
#define D_MODEL 1024
#define NH 16
#define DH 64
#define NROWS 4096  // B*T

typedef __bf16 bf16x8 __attribute__((ext_vector_type(8)));
typedef float floatx4 __attribute__((ext_vector_type(4)));
typedef short short4v __attribute__((ext_vector_type(4)));
typedef short short8v __attribute__((ext_vector_type(8)));

#define AS1 __attribute__((address_space(1)))
#define AS3 __attribute__((address_space(3)))

static __device__ __forceinline__ void gl2lds16(const unsigned short* g, unsigned short* s) {
    __builtin_amdgcn_global_load_lds((const AS1 unsigned int*)g, (AS3 unsigned int*)s, 16, 0, 0);
}

static __device__ __forceinline__ unsigned short f32_bf16(float f) {
    union { float f; unsigned int u; } c; c.f = f;
    unsigned int u = c.u;
    u = u + 0x7FFFu + ((u >> 16) & 1u);   // RNE
    return (unsigned short)(u >> 16);
}

static __device__ __forceinline__ unsigned int pack2_bf16(float a, float b) {
    return (unsigned int)f32_bf16(a) | ((unsigned int)f32_bf16(b) << 16);
}

static __device__ __forceinline__ floatx4 mfma16(bf16x8 a, bf16x8 b, floatx4 c) {
    return __builtin_amdgcn_mfma_f32_16x16x32_bf16(a, b, c, 0, 0, 0);
}

static __device__ __forceinline__ bf16x8 as_bf(short8v s) {
    union { short8v s; bf16x8 b; } u; u.s = s; return u.b;
}

#define QSCALE 0.1803368801111204f   // (1/8) * log2(e); softmax in exp2 domain
#define EXP2_SHIFT 10.0f
// s_waitcnt imm: vmcnt[3:0], expcnt[6:4]=7 (nowait), lgkmcnt[11:8]=0xF (nowait)
#define WAITCNT_VM(n) (0x0F70 | (n))

// ---------------- fused conversion kernel ----------------
__global__ __launch_bounds__(256) void k_conv_all(const float* __restrict__ x,
                                                  const float* __restrict__ Wq,
                                                  const float* __restrict__ Wk,
                                                  const float* __restrict__ Wv,
                                                  const float* __restrict__ Wo,
                                                  unsigned short* __restrict__ x_bf,
                                                  unsigned short* __restrict__ wqkv_bf,
                                                  unsigned short* __restrict__ wo_bf) {
    int b = blockIdx.x, t = threadIdx.x;
    if (b < 4096) {
        int i = b * 1024 + t * 4;
        float4 v = *(const float4*)(x + i);
        uint2 o;
        o.x = pack2_bf16(v.x, v.y);
        o.y = pack2_bf16(v.z, v.w);
        *(uint2*)(x_bf + i) = o;
    } else if (b < 7168) {
        int idx = b - 4096;
        int tensor = idx >> 10, np = idx & 1023;
        const float* src = tensor == 0 ? Wq : tensor == 1 ? Wk : Wv;
        int f = (np & 63) * 16 + (np >> 6);
        int c = t * 4;
        float4 v = *(const float4*)(src + (long)f * D_MODEL + c);
        uint2 o;
        o.x = pack2_bf16(v.x, v.y);
        o.y = pack2_bf16(v.z, v.w);
        *(uint2*)(wqkv_bf + ((long)tensor * D_MODEL + np) * D_MODEL + c) = o;
    } else {
        int n = b - 7168;
        int fp = t * 4;
        const float* row = Wo + (long)n * D_MODEL;
        unsigned short o[4];
        #pragma unroll
        for (int k = 0; k < 4; k++) {
            int f = fp + k;
            o[k] = f32_bf16(row[(f & 63) * 16 + (f >> 6)]);
        }
        *(uint2*)(wo_bf + (long)n * D_MODEL + fp) = *(const uint2*)o;
    }
}

// ---------------- GEMM: C = A(bf16) @ W(bf16)^T, K = 1024 ----------------
// Double-buffered LDS K-loop; raw s_barrier + manual partial vmcnt — no compiler
// vmcnt(0) drains anywhere in the loop. XOR-swizzled LDS, XCD-aware block swizzle.
// MODE 0: fused QKV (W stacked 3072x1024); grid 768. MODE 1: O-proj; grid 512.
template <int BN, int MODE>
__global__ __launch_bounds__(256) void k_gemm(const unsigned short* __restrict__ A,
                                              const unsigned short* __restrict__ W,
                                              const float* __restrict__ b0,
                                              const float* __restrict__ b1,
                                              const float* __restrict__ b2,
                                              const float* __restrict__ resid,
                                              unsigned short* __restrict__ out_bf,
                                              unsigned short* __restrict__ vtg,
                                              float* __restrict__ out_f32) {
    constexpr int NT = BN / 32;
    constexpr int NCB = BN / 32;
    constexpr int NDMA = 4 + NCB;            // DMA instrs per thread per stage
    __shared__ unsigned short lds_a[2 * 128 * 64];
    __shared__ unsigned short lds_b[2 * BN * 64];
    const int tid = threadIdx.x;
    const int w = tid >> 6, l = tid & 63;
    const int lrow = l & 15, lq = l >> 4;
    const int wm = (w >> 1) * 64, wn = (w & 1) * (BN / 2);
    const int L = blockIdx.x;
    const int bx = (L & 7) * 4 + ((L >> 3) & 3);
    const int by = L >> 5;
    const long am0 = (long)bx * 128;
    const long wn0 = (long)by * BN;

    floatx4 acc[4][NT] = {};
    const int grow = l >> 3;
    const int gcol = ((l & 7) ^ grow) * 8;   // column-group XOR swizzle (global side)
    const int sw8 = (lrow & 7);

    auto stage = [&](int ki, int sel) {
        unsigned short* la = lds_a + sel * 8192;
        unsigned short* lb = lds_b + sel * (BN * 64);
        int k0 = ki * 64;
        #pragma unroll
        for (int c = 0; c < 4; c++) {
            int chunk = w * 4 + c;
            gl2lds16(A + (am0 + chunk * 8 + grow) * D_MODEL + k0 + gcol, la + chunk * 512);
        }
        #pragma unroll
        for (int c = 0; c < NCB; c++) {
            int chunk = w * NCB + c;
            gl2lds16(W + (wn0 + chunk * 8 + grow) * D_MODEL + k0 + gcol, lb + chunk * 512);
        }
    };

    stage(0, 0);

    for (int i = 0; i < 16; i++) {
        const int cur = i & 1;
        if (i < 15) {
            stage(i + 1, 1 - cur);
            __builtin_amdgcn_s_waitcnt(WAITCNT_VM(NDMA));  // drain stage(i), keep stage(i+1)
        } else {
            __builtin_amdgcn_s_waitcnt(WAITCNT_VM(0));
        }
        __builtin_amdgcn_s_barrier();

        const unsigned short* la = lds_a + cur * 8192;
        const unsigned short* lb = lds_b + cur * (BN * 64);
        bf16x8 af[4][2], bf[NT][2];
        #pragma unroll
        for (int mt = 0; mt < 4; mt++)
            #pragma unroll
            for (int ks = 0; ks < 2; ks++)
                af[mt][ks] = *(const bf16x8*)(la + (wm + mt * 16 + lrow) * 64 +
                                              (((ks * 4 + lq) ^ sw8) * 8));
        #pragma unroll
        for (int nt = 0; nt < NT; nt++)
            #pragma unroll
            for (int ks = 0; ks < 2; ks++)
                bf[nt][ks] = *(const bf16x8*)(lb + (wn + nt * 16 + lrow) * 64 +
                                              (((ks * 4 + lq) ^ sw8) * 8));
        #pragma unroll
        for (int mt = 0; mt < 4; mt++)
            #pragma unroll
            for (int nt = 0; nt < NT; nt++)
                #pragma unroll
                for (int ks = 0; ks < 2; ks++)
                    acc[mt][nt] = mfma16(af[mt][ks], bf[nt][ks], acc[mt][nt]);
        __builtin_amdgcn_s_barrier();   // raw: reads of buf[cur] done before restage (i+2)
    }

    if (MODE == 0) {
        int tensor = by >> 3;                    // 0=Q 1=K 2=V
        int nbase = (by & 7) * 128;
        const float* bias = tensor == 0 ? b0 : tensor == 1 ? b1 : b2;
        float scale = tensor == 0 ? QSCALE : 1.0f;
        if (tensor < 2) {
            unsigned short* outt = out_bf + (size_t)tensor * (32u * T_SEQ * DH);
            #pragma unroll
            for (int mt = 0; mt < 4; mt++) {
                #pragma unroll
                for (int nt = 0; nt < NT; nt++) {
                    int n = nbase + wn + nt * 16 + lrow;     // n' = h*64+d
                    int h = n >> 6, d = n & 63;
                    float bb = bias[d * 16 + h];
                    #pragma unroll
                    for (int r = 0; r < 4; r++) {
                        int row = (int)am0 + wm + mt * 16 + lq * 4 + r;
                        float v = (acc[mt][nt][r] + bb) * scale;
                        int b = row >> 11, i = row & 2047;
                        long idx = ((long)(b * 16 + h) * T_SEQ + i) * DH + d;
                        outt[idx] = f32_bf16(v);
                    }
                }
            }
        } else {
            int row0 = (int)am0 + wm;                    // multiple of 64
            int b = row0 >> 11;
            int blk = (row0 & 2047) >> 6;
            // vtg j'-slot permutation: position g*32 + lq*8 + nt'*4 + r holds
            // token mt*16 + lq*4 + r where mt = g*2 + nt'. This makes
            // pf[2g]||pf[2g+1] a valid K=32 B-operand against the V-frag read
            // at granule g*4+lq in k_attn's PV (j-permutation-invariant softmax).
            #pragma unroll
            for (int nt = 0; nt < NT; nt++) {
                int n = nbase + wn + nt * 16 + lrow;
                int h = n >> 6, d = n & 63;
                float bb = bias[d * 16 + h];
                long base = (((long)(b * 16 + h) * 64 + d) * 32 + blk) * 64;
                #pragma unroll
                for (int mt = 0; mt < 4; mt++) {
                    uint2 o;
                    o.x = pack2_bf16(acc[mt][nt][0] + bb, acc[mt][nt][1] + bb);
                    o.y = pack2_bf16(acc[mt][nt][2] + bb, acc[mt][nt][3] + bb);
                    *(uint2*)(vtg + base + (mt >> 1) * 32 + lq * 8 + (mt & 1) * 4) = o;
                }
            }
        }
    } else {
        #pragma unroll
        for (int mt = 0; mt < 4; mt++) {
            #pragma unroll
            for (int nt = 0; nt < NT; nt++) {
                int n = (int)wn0 + wn + nt * 16 + lrow;
                float bb = b0[n];
                #pragma unroll
                for (int r = 0; r < 4; r++) {
                    int row = (int)am0 + wm + mt * 16 + lq * 4 + r;
                    long idx = (long)row * D_MODEL + n;
                    out_f32[idx] = acc[mt][nt][r] + bb + resid[idx];
                }
            }
        }
    }
}

// ---------------- attention: S^T trick + cross-tile software pipeline --------
// r8: PV and the denominator use K=32 mfma_f32_16x16x32_bf16 instead of the
// legacy K=16 _1k shape (which occupies the matrix pipe for the same cycles at
// half the FLOPs on CDNA4). Enabled by permuting j-slots inside each 64-token
// block of the vtg layout so that concatenating two adjacent nt P-fragments
// yields a valid K=32 operand. MFMA instrs per wave-tile: 56 -> 36.
__global__ __launch_bounds__(256) void k_attn(const unsigned short* __restrict__ q_ws,
                                              const unsigned short* __restrict__ k_ws,
                                              const unsigned short* __restrict__ vtg,
                                              unsigned short* __restrict__ att) {
    __shared__ unsigned short kbuf[2 * 64 * 64];
    __shared__ unsigned short vbuf[2 * 64 * 64];
    const int tid = threadIdx.x;
    const int w = tid >> 6, l = tid & 63;
    const int lrow = l & 15, lq = l >> 4;
    const int sw = lrow & 7;
    const int L = blockIdx.x;
    const int bh = (L & 7) * 4 + ((L >> 3) & 3);   // 4 bh per XCD -> K/V L2-resident
    const int i0 = (L >> 5) * 128;
    const unsigned short* kh = k_ws + (long)bh * T_SEQ * DH;
    const unsigned short* vh = vtg + (long)bh * 64 * T_SEQ;  // [d][blk][j'-permuted]

    const int rl = l >> 3;                     // staging: row within 8-row chunk
    const int gl = ((l & 7) ^ rl) * 8;         // staging: swizzled granule (shorts)

    bf16x8 qf[2][2];
    #pragma unroll
    for (int qt = 0; qt < 2; qt++) {
        const unsigned short* qp =
            q_ws + ((long)bh * T_SEQ + i0 + w * 32 + qt * 16 + lrow) * DH + lq * 8;
        qf[qt][0] = *(const bf16x8*)qp;
        qf[qt][1] = *(const bf16x8*)(qp + 32);
    }
    floatx4 o_acc[2][4] = {};
    floatx4 l_acc[2] = {};
    const short8v ones8s = {0x3F80, 0x3F80, 0x3F80, 0x3F80, 0x3F80, 0x3F80, 0x3F80, 0x3F80};
    const bf16x8 ones8 = as_bf(ones8s);

    auto stage_k = [&](int jt, int sel) {
        unsigned short* kd = kbuf + sel * 4096 + (w * 2) * 512;
        #pragma unroll
        for (int c = 0; c < 2; c++) {
            int row = w * 16 + c * 8 + rl;     // 0..63
            gl2lds16(kh + ((long)(jt * 64 + row)) * 64 + gl, kd + c * 512);
        }
    };
    auto stage_v = [&](int jt, int sel) {
        unsigned short* vd = vbuf + sel * 4096 + (w * 2) * 512;
        #pragma unroll
        for (int c = 0; c < 2; c++) {
            int row = w * 16 + c * 8 + rl;
            gl2lds16(vh + ((long)row * 32 + jt) * 64 + gl, vd + c * 512);
        }
    };

    // S^T - 10 for both q-tiles; K-frags read once (single-granule b128s)
    auto qk = [&](const unsigned short* kb_, floatx4 (&s0)[4], floatx4 (&s1)[4]) {
        #pragma unroll
        for (int nt = 0; nt < 4; nt++) {
            const unsigned short* kp = kb_ + (nt * 16 + lrow) * 64;
            bf16x8 ka = *(const bf16x8*)(kp + ((lq ^ sw) * 8));
            bf16x8 kb = *(const bf16x8*)(kp + (((lq + 4) ^ sw) * 8));
            floatx4 c0 = {-EXP2_SHIFT, -EXP2_SHIFT, -EXP2_SHIFT, -EXP2_SHIFT};
            floatx4 c1 = c0;
            c0 = mfma16(ka, qf[0][0], c0);
            c0 = mfma16(kb, qf[0][1], c0);
            c1 = mfma16(ka, qf[1][0], c1);
            c1 = mfma16(kb, qf[1][1], c1);
            s0[nt] = c0;
            s1[nt] = c1;
        }
    };

    // p = exp2(s); pack 4 bf16 (truncation via perm) — no l_acc here
    auto sp4 = [&](floatx4 s) -> short4v {
        float p0 = __builtin_amdgcn_exp2f(s[0]);
        float p1 = __builtin_amdgcn_exp2f(s[1]);
        float p2 = __builtin_amdgcn_exp2f(s[2]);
        float p3 = __builtin_amdgcn_exp2f(s[3]);
        uint2 pk;
        pk.x = __builtin_amdgcn_perm(__float_as_uint(p1), __float_as_uint(p0), 0x07060302);
        pk.y = __builtin_amdgcn_perm(__float_as_uint(p3), __float_as_uint(p2), 0x07060302);
        union { uint2 u; short4v s4; } cv; cv.u = pk;
        return cv.s4;
    };

    // O^T += V^T * P for one dt, both q-tiles, K=32 (two j-halves g=0/1)
    auto pv_dt = [&](const unsigned short* vb_, int dt,
                     short8v (&p0)[2], short8v (&p1)[2]) {
        const unsigned short* vp = vb_ + (dt * 16 + lrow) * 64;
        bf16x8 vg0 = *(const bf16x8*)(vp + ((lq ^ sw) * 8));         // granule lq   (j 0..31)
        bf16x8 vg1 = *(const bf16x8*)(vp + (((4 + lq) ^ sw) * 8));   // granule 4+lq (j 32..63)
        o_acc[0][dt] = mfma16(vg0, as_bf(p0[0]), o_acc[0][dt]);
        o_acc[0][dt] = mfma16(vg1, as_bf(p0[1]), o_acc[0][dt]);
        o_acc[1][dt] = mfma16(vg0, as_bf(p1[0]), o_acc[1][dt]);
        o_acc[1][dt] = mfma16(vg1, as_bf(p1[1]), o_acc[1][dt]);
    };

    // one pipelined tile: QK(t) then { PV(t-1) ∥ exp2/pack(t) } interleaved
    auto tile_body = [&](const unsigned short* kb_, const unsigned short* vb_,
                         short8v (&pp0)[2], short8v (&pp1)[2],
                         short8v (&pc0)[2], short8v (&pc1)[2]) {
        floatx4 s0[4], s1[4];
        qk(kb_, s0, s1);
        #pragma unroll
        for (int g = 0; g < 2; g++) {
            pv_dt(vb_, 2 * g, pp0, pp1);          // MFMA pipe (prev tile's P)
            short4v t00 = sp4(s0[2 * g]);          // TRANS/VALU (this tile's P)
            short4v t10 = sp4(s1[2 * g]);
            pv_dt(vb_, 2 * g + 1, pp0, pp1);
            short4v t01 = sp4(s0[2 * g + 1]);
            short4v t11 = sp4(s1[2 * g + 1]);
            pc0[g] = __builtin_shufflevector(t00, t01, 0, 1, 2, 3, 4, 5, 6, 7);
            pc1[g] = __builtin_shufflevector(t10, t11, 0, 1, 2, 3, 4, 5, 6, 7);
            l_acc[0] = mfma16(ones8, as_bf(pc0[g]), l_acc[0]);
            l_acc[1] = mfma16(ones8, as_bf(pc1[g]), l_acc[1]);
        }
    };

    short8v pA0[2], pA1[2], pB0[2], pB1[2];

    // ---- prologue: tile 0 (no PV yet). Stage K(0); then K(1)+V(0) in flight.
    stage_k(0, 0);
    stage_k(1, 1);
    stage_v(0, 0);
    __builtin_amdgcn_s_waitcnt(WAITCNT_VM(4));   // drain qf + K(0), keep K(1)+V(0)
    __builtin_amdgcn_s_barrier();
    {
        floatx4 s0[4], s1[4];
        qk(kbuf, s0, s1);
        #pragma unroll
        for (int g = 0; g < 2; g++) {
            short4v t00 = sp4(s0[2 * g]);
            short4v t01 = sp4(s0[2 * g + 1]);
            short4v t10 = sp4(s1[2 * g]);
            short4v t11 = sp4(s1[2 * g + 1]);
            pA0[g] = __builtin_shufflevector(t00, t01, 0, 1, 2, 3, 4, 5, 6, 7);
            pA1[g] = __builtin_shufflevector(t10, t11, 0, 1, 2, 3, 4, 5, 6, 7);
            l_acc[0] = mfma16(ones8, as_bf(pA0[g]), l_acc[0]);
            l_acc[1] = mfma16(ones8, as_bf(pA1[g]), l_acc[1]);
        }
    }
    __builtin_amdgcn_s_barrier();   // all waves done reading kbuf[0] before restage

    // ---- main loop: tiles 1..30, explicitly paired so P-state rotates in regs
    for (int t = 1; t < 31; t += 2) {
        // tile t (odd): consume pA -> produce pB
        stage_k(t + 1, (t + 1) & 1);
        stage_v(t, t & 1);
        __builtin_amdgcn_s_waitcnt(WAITCNT_VM(4));   // drain K(t)+V(t-1)
        __builtin_amdgcn_s_barrier();
        tile_body(kbuf + (t & 1) * 4096, vbuf + ((t - 1) & 1) * 4096,
                  pA0, pA1, pB0, pB1);
        __builtin_amdgcn_s_barrier();
        // tile t+1 (even): consume pB -> produce pA
        stage_k(t + 2, t & 1);
        stage_v(t + 1, (t + 1) & 1);
        __builtin_amdgcn_s_waitcnt(WAITCNT_VM(4));   // drain K(t+1)+V(t)
        __builtin_amdgcn_s_barrier();
        tile_body(kbuf + ((t + 1) & 1) * 4096, vbuf + (t & 1) * 4096,
                  pB0, pB1, pA0, pA1);
        __builtin_amdgcn_s_barrier();
    }

    // ---- tile 31 (last): stage V(31) only; consume pA -> produce pB
    stage_v(31, 1);
    __builtin_amdgcn_s_waitcnt(WAITCNT_VM(2));       // drain K(31)+V(30), keep V(31)
    __builtin_amdgcn_s_barrier();
    tile_body(kbuf + 4096, vbuf + 0, pA0, pA1, pB0, pB1);
    __builtin_amdgcn_s_barrier();

    // ---- epilogue: PV(31)
    __builtin_amdgcn_s_waitcnt(WAITCNT_VM(0));       // own V(31) DMA done
    __builtin_amdgcn_s_barrier();                    // everyone's V(31) DMA done
    #pragma unroll
    for (int dt = 0; dt < 4; dt++) pv_dt(vbuf + 4096, dt, pB0, pB1);

    int h = bh & 15, b = bh >> 4;
    #pragma unroll
    for (int qt = 0; qt < 2; qt++) {
        float rl2 = 1.0f / l_acc[qt][0];
        int i = i0 + w * 32 + qt * 16 + lrow;
        unsigned short* orow = att + ((long)(b * T_SEQ + i)) * D_MODEL + h * 64;
        #pragma unroll
        for (int dt = 0; dt < 4; dt++) {
            uint2 o;
            o.x = pack2_bf16(o_acc[qt][dt][0] * rl2, o_acc[qt][dt][1] * rl2);
            o.y = pack2_bf16(o_acc[qt][dt][2] * rl2, o_acc[qt][dt][3] * rl2);
            *(uint2*)(orow + dt * 16 + lq * 4) = o;
        }
    }
}

// ---------------- LayerNorm in-place on d_out ----------------
__global__ __launch_bounds__(256) void k_ln(float* __restrict__ io,
                                            const float* __restrict__ gamma,
                                            const float* __restrict__ beta) {
    int row = blockIdx.x, t = threadIdx.x;
    float* p = io + (long)row * D_MODEL + t * 4;
    float4 v = *(float4*)p;
    float s = v.x + v.y + v.z + v.w;
    float ss = v.x * v.x + v.y * v.y + v.z * v.z + v.w * v.w;
    #pragma unroll
    for (int m = 1; m < 64; m <<= 1) {
        s += __shfl_xor(s, m);
        ss += __shfl_xor(ss, m);
    }
    __shared__ float red[8];
    if ((t & 63) == 0) { red[t >> 6] = s; red[4 + (t >> 6)] = ss; }
    __syncthreads();
    s = red[0] + red[1] + red[2] + red[3];
    ss = red[4] + red[5] + red[6] + red[7];
    float mu = s * (1.0f / 1024.0f);
    float var = ss * (1.0f / 1024.0f) - mu * mu;
    float rstd = rsqrtf(var + 1e-5f);
    float4 g = *(const float4*)(gamma + t * 4);
    float4 be = *(const float4*)(beta + t * 4);
    float4 o;
    o.x = (v.x - mu) * rstd * g.x + be.x;
    o.y = (v.y - mu) * rstd * g.y + be.y;
    o.z = (v.z - mu) * rstd * g.z + be.z;
    o.w = (v.w - mu) * rstd * g.w + be.w;
    *(float4*)p = o;
}

extern "C" void kernel_launch(void* const* d_in, const int* in_sizes, int n_in,
                              void* d_out, int out_size, void* d_ws, size_t ws_size,
                              hipStream_t stream) {
    const float* x = (const float*)d_in[0];
    const float* Wq = (const float*)d_in[1];
    const float* bq = (const float*)d_in[2];
    const float* Wk = (const float*)d_in[3];
    const float* bk = (const float*)d_in[4];
    const float* Wv = (const float*)d_in[5];
    const float* bv = (const float*)d_in[6];
    const float* Wo = (const float*)d_in[7];
    const float* bo = (const float*)d_in[8];
    const float* gamma = (const float*)d_in[9];
    const float* beta = (const float*)d_in[10];
    float* out = (float*)d_out;

    char* ws = (char*)d_ws;
    unsigned short* x_bf = (unsigned short*)(ws);                       // 0-8 MB (reused as att)
    unsigned short* wqkv_bf = (unsigned short*)(ws + ((size_t)8 << 20));// 8-14 MB
    unsigned short* wo_bf = (unsigned short*)(ws + ((size_t)14 << 20)); // 14-16 MB
    unsigned short* qkv_ws = (unsigned short*)(ws + ((size_t)16 << 20));// 16-40 MB (q|k|vt)
    unsigned short* att = x_bf;  // alias: x_bf dead after QKV GEMM

    unsigned short* q_ws = qkv_ws;
    unsigned short* k_ws = qkv_ws + (size_t)32 * T_SEQ * DH;
    unsigned short* vtg = qkv_ws + (size_t)64 * T_SEQ * DH;

    k_conv_all<<<8192, 256, 0, stream>>>(x, Wq, Wk, Wv, Wo, x_bf, wqkv_bf, wo_bf);

    // fused QKV GEMM: N = 3072, 1D grid with XCD swizzle
    k_gemm<128, 0><<<768, 256, 0, stream>>>(
        x_bf, wqkv_bf, bq, bk, bv, nullptr, qkv_ws, vtg, nullptr);

    k_attn<<<512, 256, 0, stream>>>(q_ws, k_ws, vtg, att);

    // O-projection + bias + residual: N = 1024, 1D grid with XCD swizzle
    k_gemm<64, 1><<<512, 256, 0, stream>>>(
        att, wo_bf, bo, nullptr, nullptr, x, nullptr, nullptr, out);

    k_ln<<<NROWS, 256, 0, stream>>>(out, gamma, beta);
}